// Round 6
// baseline (1140.145 us; speedup 1.0000x reference)
//
#include <hip/hip_runtime.h>
#include <cmath>

#define E_INC   393216
#define NN_     12288
#define MM_     16384
#define FDIM    256
#define CDIM    128
#define PKEYS   128
#define LCAP    6144

__host__ __device__ inline int stBase(int r){ return r<3 ? r*(NN_+1) : 3*(NN_+1) + (r-3)*(MM_+1); }
__host__ __device__ inline int nParts(int r){ return (r<3 ? NN_ : MM_) / PKEYS; }  // 96 or 128

__device__ __forceinline__ float lrelu(float v){ return v >= 0.0f ? v : 0.2f*v; }

struct Ptrs6 { const int* p[6]; };

// ---------------- CSR build: two-level partition (write-locality) ----------------
__global__ __launch_bounds__(256) void coarse_hist(Ptrs6 keys, int* __restrict__ ccnt){
  __shared__ int h[PKEYS];
  int r = blockIdx.y, t = threadIdx.x;
  if (t < PKEYS) h[t] = 0;
  __syncthreads();
  int base = blockIdx.x * 4096;
  const int* ka = keys.p[r];
  for (int j=0;j<16;++j) atomicAdd(&h[ka[base + j*256 + t] >> 7], 1);
  __syncthreads();
  if (t < PKEYS) atomicAdd(&ccnt[r*PKEYS + t], h[t]);
}

__global__ __launch_bounds__(128) void coarse_scan(const int* __restrict__ ccnt,
                                                   int* __restrict__ cstart,
                                                   int* __restrict__ ccur){
  int r = blockIdx.x, t = threadIdx.x;
  int P = nParts(r);
  int c = (t < P) ? ccnt[r*PKEYS + t] : 0;
  __shared__ int sd[128];
  sd[t] = c; __syncthreads();
  for (int ofs=1; ofs<128; ofs<<=1){
    int v = (t>=ofs) ? sd[t-ofs] : 0;
    __syncthreads(); sd[t] += v; __syncthreads();
  }
  int excl = sd[t] - c;
  cstart[r*129 + t] = excl;
  ccur[r*PKEYS + t] = excl;
  if (t == 127) cstart[r*129 + 128] = sd[127];
}

__global__ __launch_bounds__(256) void part_scatter(Ptrs6 keys, int* __restrict__ ccur,
                                                    int* __restrict__ pbuf){
  __shared__ int h[PKEYS];
  __shared__ int cur[PKEYS];
  int r = blockIdx.y, t = threadIdx.x;
  if (t < PKEYS) h[t] = 0;
  __syncthreads();
  int base = blockIdx.x * 4096;
  const int* ka = keys.p[r];
  int myk[16];
  for (int j=0;j<16;++j){
    myk[j] = ka[base + j*256 + t] >> 7;
    atomicAdd(&h[myk[j]], 1);
  }
  __syncthreads();
  if (t < PKEYS) cur[t] = atomicAdd(&ccur[r*PKEYS + t], h[t]);
  __syncthreads();
  int* pb = pbuf + (size_t)r * E_INC;
  for (int j=0;j<16;++j){
    int pos = atomicAdd(&cur[myk[j]], 1);
    pb[pos] = base + j*256 + t;
  }
}

__global__ __launch_bounds__(256) void fine_build(Ptrs6 keys, const int* __restrict__ cstart,
                                                  const int* __restrict__ pbuf,
                                                  int* __restrict__ starts,
                                                  int* __restrict__ lists){
  __shared__ unsigned short kb[LCAP];
  __shared__ int ob[LCAP];
  __shared__ int h[PKEYS], ls[PKEYS], lc[PKEYS];
  int r = blockIdx.y, p = blockIdx.x, t = threadIdx.x;
  int P = nParts(r);
  if (p >= P) return;
  int lo = cstart[r*129 + p], hi = cstart[r*129 + p + 1];
  int len = hi - lo;
  if (t < PKEYS) h[t] = 0;
  __syncthreads();
  const int* ka = keys.p[r];
  const int* pb = pbuf + (size_t)r * E_INC;
  int* lst = lists + (size_t)r * E_INC;
  int kbase = p << 7;
  int sb = stBase(r);
  if (len <= LCAP){
    for (int i=t; i<len; i+=256){
      int e = pb[lo+i];
      int k = ka[e] - kbase;
      kb[i] = (unsigned short)k;
      atomicAdd(&h[k], 1);
    }
    __syncthreads();
    if (t == 0){ int run = 0; for (int k=0;k<PKEYS;++k){ ls[k]=run; lc[k]=run; run+=h[k]; } }
    __syncthreads();
    for (int i=t; i<len; i+=256){
      int pos = atomicAdd(&lc[kb[i]], 1);
      ob[pos] = pb[lo+i];
    }
    __syncthreads();
    for (int i=t; i<len; i+=256) lst[lo+i] = ob[i];
    if (t < PKEYS) starts[sb + kbase + t] = lo + ls[t];
  } else {
    for (int i=t; i<len; i+=256) atomicAdd(&h[ka[pb[lo+i]] - kbase], 1);
    __syncthreads();
    if (t == 0){ int run = 0; for (int k=0;k<PKEYS;++k){ ls[k]=run; lc[k]=run; run+=h[k]; } }
    __syncthreads();
    for (int i=t; i<len; i+=256){
      int e = pb[lo+i];
      int pos = atomicAdd(&lc[ka[e] - kbase], 1);
      lst[lo+pos] = e;
    }
    if (t < PKEYS) starts[sb + kbase + t] = lo + ls[t];
  }
  if (p == P-1 && t == 0) starts[sb + (r<3 ? NN_ : MM_)] = hi;
}

// sort each bucket ascending -> accumulation order == numpy sequential order.
__global__ __launch_bounds__(256) void sortb_kernel(const int* __restrict__ starts,
                                                    int* __restrict__ lists){
  int r = blockIdx.y;
  int nb = (r<3) ? NN_ : MM_;
  int wid = (blockIdx.x*256 + threadIdx.x) >> 6;
  int lane = threadIdx.x & 63;
  if (wid >= nb) return;
  int sb = stBase(r);
  int lo = starts[sb+wid], hi = starts[sb+wid+1];
  int len = hi - lo;
  if (len <= 1) return;
  int* lst = lists + (size_t)r*E_INC;
  if (len <= 64){
    int v = (lane < len) ? lst[lo+lane] : 0x7fffffff;
#pragma unroll
    for (int k = 2; k <= 64; k <<= 1){
#pragma unroll
      for (int j = k>>1; j > 0; j >>= 1){
        int o = __shfl_xor(v, j);
        bool up    = ((lane & k) == 0);
        bool lower = ((lane & j) == 0);
        int mn = min(v,o), mx = max(v,o);
        v = (lower == up) ? mn : mx;
      }
    }
    if (lane < len) lst[lo+lane] = v;
  } else if (lane == 0) {
    for (int i=lo+1; i<hi; ++i){
      int key = lst[i]; int j = i-1;
      while (j>=lo && lst[j]>key){ lst[j+1]=lst[j]; --j; }
      lst[j+1]=key;
    }
  }
}

// ---------------- build-time index resolution (loop-invariant across layers) ----------------
struct AuxH { const int* el[3]; };
__global__ __launch_bounds__(256) void aux_h(AuxH a, int* __restrict__ eposb){
  int k = blockIdx.y;
  int i = blockIdx.x*256 + threadIdx.x;
  int e = a.el[k][i];
  eposb[(size_t)k*E_INC + e] = i;
}

struct AuxN { const int* nl[3]; const int* ei[3]; };
__global__ __launch_bounds__(256) void aux_n(AuxN a, const int* __restrict__ stb_,
                                             const int* __restrict__ eposb,
                                             const float* __restrict__ hw,
                                             int* __restrict__ eilb, int* __restrict__ enpb,
                                             float* __restrict__ dinvb){
  int g = blockIdx.x*256 + threadIdx.x;
  int w = g >> 6, lane = g & 63, k = blockIdx.y;
  if (w >= NN_) return;
  const int* st = stb_ + stBase(k);
  int lo = st[w], hi = st[w+1];
  const int* nl = a.nl[k];
  const int* ei = a.ei[k];
  const int* ep = eposb + (size_t)k*E_INC;
  int* eo = eilb + (size_t)k*E_INC;
  int* po = enpb + (size_t)k*E_INC;
  double sd = 0.0;
  for (int i=lo+lane; i<hi; i+=64){
    int e = nl[i]; int m = ei[e];
    eo[i] = m; po[i] = ep[e];
    sd += (double)hw[m];
  }
  for (int ofs=32; ofs; ofs>>=1) sd += __shfl_xor(sd, ofs);
  if (lane==0){
    float D = (float)sd;
    dinvb[(size_t)k*NN_ + w] = (D > 0.0f) ? 1.0f/D : 0.0f;
  }
}

// length-balanced assignment: counting-sort ids by bucket length (layer-invariant).
__global__ __launch_bounds__(256) void perm_build(const int* __restrict__ stb_,
                                                  int* __restrict__ nperm,
                                                  int* __restrict__ eperm){
  int r = blockIdx.x;              // 0..5
  int nb = (r<3) ? NN_ : MM_;
  const int* st = stb_ + stBase(r);
  int* pm = (r<3) ? (nperm + (size_t)r*NN_) : (eperm + (size_t)(r-3)*MM_);
  __shared__ int hist[256], basep[256];
  int t = threadIdx.x;
  hist[t] = 0;
  __syncthreads();
  for (int i=t; i<nb; i+=256){
    int len = st[i+1]-st[i]; if (len>255) len=255;
    atomicAdd(&hist[len],1);
  }
  __syncthreads();
  if (t==0){ int run=0; for(int b=0;b<256;++b){ basep[b]=run; run+=hist[b]; } }
  __syncthreads();
  hist[t] = 0;
  __syncthreads();
  for (int i=t; i<nb; i+=256){
    int len = st[i+1]-st[i]; if (len>255) len=255;
    int pos = basep[len] + atomicAdd(&hist[len],1);
    pm[pos] = i;
  }
}

// ---------------- fp32 GEMMs ----------------
__global__ __launch_bounds__(256)
void gemm_nn(const float* __restrict__ A, const float* __restrict__ W,
             const float* __restrict__ bias, float* __restrict__ C,
             int N, int segShift, int act)
{
  __shared__ alignas(16) float As[16][72];
  __shared__ alignas(16) float Bs[16][72];
  int t = threadIdx.x;
  int bm = blockIdx.x * 64;
  int bn = blockIdx.y * 64;
  int seg = bm >> segShift;
  const float* Wp = W + (size_t)seg * FDIM * N;
  int tx = t & 15, ty = t >> 4;
  int arow = t >> 2, acq = (t & 3) << 2;
  int brow = t >> 4, bcol = (t & 15) << 2;

  float acc[4][4] = {};
  for (int k0 = 0; k0 < FDIM; k0 += 16){
    float4 a0 = *(const float4*)(A + (size_t)(bm+arow)*FDIM + k0 + acq);
    As[acq+0][arow]=a0.x; As[acq+1][arow]=a0.y; As[acq+2][arow]=a0.z; As[acq+3][arow]=a0.w;
    *(float4*)&Bs[brow][bcol] = *(const float4*)(Wp + (size_t)(k0+brow)*N + bn + bcol);
    __syncthreads();
#pragma unroll
    for (int kk=0; kk<16; ++kk){
      float4 av = *(const float4*)&As[kk][ty<<2];
      float4 bv = *(const float4*)&Bs[kk][tx<<2];
      float af[4] = {av.x,av.y,av.z,av.w};
      float bf[4] = {bv.x,bv.y,bv.z,bv.w};
#pragma unroll
      for (int i=0;i<4;++i)
#pragma unroll
        for (int j=0;j<4;++j) acc[i][j] = fmaf(af[i], bf[j], acc[i][j]);
    }
    __syncthreads();
  }
  int c0 = bn + (tx<<2);
  float4 bb = make_float4(0.f,0.f,0.f,0.f);
  if (bias) bb = *(const float4*)(bias + (size_t)seg*N + c0);
#pragma unroll
  for (int i=0;i<4;++i){
    float4 o = make_float4(acc[i][0],acc[i][1],acc[i][2],acc[i][3]);
    if (bias){ o.x+=bb.x; o.y+=bb.y; o.z+=bb.z; o.w+=bb.w; }
    if (act){ o.x=lrelu(o.x); o.y=lrelu(o.y); o.z=lrelu(o.z); o.w=lrelu(o.w); }
    *(float4*)(C + (size_t)(bm+(ty<<2)+i)*N + c0) = o;
  }
}

// 3-branch xl GEMM: C[z] = A @ W[z]; identical tiling/math to gemm_nn (N=FDIM, no bias/act)
__global__ __launch_bounds__(256)
void gemm_nn3(const float* __restrict__ A, const float* __restrict__ Wall,
              float* __restrict__ Call)
{
  __shared__ alignas(16) float As[16][72];
  __shared__ alignas(16) float Bs[16][72];
  int t = threadIdx.x;
  int bm = blockIdx.x * 64;
  int bn = blockIdx.y * 64;
  int z = blockIdx.z;
  const float* Wp = Wall + (size_t)z * FDIM * FDIM;
  float* C = Call + (size_t)z * NN_ * FDIM;
  int tx = t & 15, ty = t >> 4;
  int arow = t >> 2, acq = (t & 3) << 2;
  int brow = t >> 4, bcol = (t & 15) << 2;

  float acc[4][4] = {};
  for (int k0 = 0; k0 < FDIM; k0 += 16){
    float4 a0 = *(const float4*)(A + (size_t)(bm+arow)*FDIM + k0 + acq);
    As[acq+0][arow]=a0.x; As[acq+1][arow]=a0.y; As[acq+2][arow]=a0.z; As[acq+3][arow]=a0.w;
    *(float4*)&Bs[brow][bcol] = *(const float4*)(Wp + (size_t)(k0+brow)*FDIM + bn + bcol);
    __syncthreads();
#pragma unroll
    for (int kk=0; kk<16; ++kk){
      float4 av = *(const float4*)&As[kk][ty<<2];
      float4 bv = *(const float4*)&Bs[kk][tx<<2];
      float af[4] = {av.x,av.y,av.z,av.w};
      float bf[4] = {bv.x,bv.y,bv.z,bv.w};
#pragma unroll
      for (int i=0;i<4;++i)
#pragma unroll
        for (int j=0;j<4;++j) acc[i][j] = fmaf(af[i], bf[j], acc[i][j]);
    }
    __syncthreads();
  }
  int c0 = bn + (tx<<2);
#pragma unroll
  for (int i=0;i<4;++i){
    float4 o = make_float4(acc[i][0],acc[i][1],acc[i][2],acc[i][3]);
    *(float4*)(C + (size_t)(bm+(ty<<2)+i)*FDIM + c0) = o;
  }
}

__global__ __launch_bounds__(256)
void gemm_nt(const float* __restrict__ A, const float* __restrict__ B,
             float* __restrict__ C, int ldc, int colOff)
{
  __shared__ alignas(16) float As[16][132];
  __shared__ alignas(16) float Bs[16][132];
  int t = threadIdx.x;
  int bm = blockIdx.x * 128;
  int bn = blockIdx.y * 128;
  int tx = t & 15, ty = t >> 4;
  int arow = t >> 1, akq = (t & 1) << 3;

  float acc[8][8] = {};
  for (int k0 = 0; k0 < CDIM; k0 += 16){
    const float* ap = A + (size_t)(bm+arow)*CDIM + k0 + akq;
    float4 a0 = *(const float4*)(ap);
    float4 a1 = *(const float4*)(ap + 4);
    As[akq+0][arow]=a0.x; As[akq+1][arow]=a0.y; As[akq+2][arow]=a0.z; As[akq+3][arow]=a0.w;
    As[akq+4][arow]=a1.x; As[akq+5][arow]=a1.y; As[akq+6][arow]=a1.z; As[akq+7][arow]=a1.w;
    const float* bp = B + (size_t)(bn+arow)*CDIM + k0 + akq;
    float4 b0 = *(const float4*)(bp);
    float4 b1 = *(const float4*)(bp + 4);
    Bs[akq+0][arow]=b0.x; Bs[akq+1][arow]=b0.y; Bs[akq+2][arow]=b0.z; Bs[akq+3][arow]=b0.w;
    Bs[akq+4][arow]=b1.x; Bs[akq+5][arow]=b1.y; Bs[akq+6][arow]=b1.z; Bs[akq+7][arow]=b1.w;
    __syncthreads();
#pragma unroll
    for (int kk=0; kk<16; ++kk){
      float4 x0 = *(const float4*)&As[kk][ty<<3];
      float4 x1 = *(const float4*)&As[kk][(ty<<3)+4];
      float4 y0 = *(const float4*)&Bs[kk][tx<<3];
      float4 y1 = *(const float4*)&Bs[kk][(tx<<3)+4];
      float af[8] = {x0.x,x0.y,x0.z,x0.w,x1.x,x1.y,x1.z,x1.w};
      float bf[8] = {y0.x,y0.y,y0.z,y0.w,y1.x,y1.y,y1.z,y1.w};
#pragma unroll
      for (int i=0;i<8;++i)
#pragma unroll
        for (int j=0;j<8;++j) acc[i][j] = fmaf(af[i], bf[j], acc[i][j]);
    }
    __syncthreads();
  }
  int c0 = colOff + bn + (tx<<3);
#pragma unroll
  for (int i=0;i<8;++i){
    float* cp = C + (size_t)(bm+(ty<<3)+i)*ldc + c0;
    *(float4*)(cp)   = make_float4(acc[i][0],acc[i][1],acc[i][2],acc[i][3]);
    *(float4*)(cp+4) = make_float4(acc[i][4],acc[i][5],acc[i][6],acc[i][7]);
  }
}

// ---------------- attention scalars (hoisted + fused) ----------------
__global__ __launch_bounds__(256)
void vv_all(const float* __restrict__ Wh1, const float* __restrict__ Wh2,
            const float* __restrict__ att1, const float* __restrict__ att2,
            float* __restrict__ vvb)
{
  int g = blockIdx.x*256 + threadIdx.x;
  int w = g >> 6, lane = g & 63;
  if (w >= 6*FDIM) return;
  int cfg = w >> 8, rr = w & 255;
  int l = cfg / 3, k = cfg % 3;
  const float* r = (l ? Wh2 : Wh1) + (size_t)k*FDIM*FDIM + (size_t)rr*FDIM;
  const float* vec = (l ? att2 : att1) + (size_t)k*2*FDIM + FDIM;
  double s = 0.0;
#pragma unroll
  for (int c=lane; c<FDIM; c+=64) s = fma((double)r[c], (double)vec[c], s);
  for (int ofs=32; ofs; ofs>>=1) s += __shfl_down(s, ofs);
  if (lane==0) vvb[cfg*FDIM + rr] = (float)s;
}

__global__ __launch_bounds__(256)
void s2_all(const float* __restrict__ hattr, const float* __restrict__ vvb,
            float* __restrict__ s2all)
{
  __shared__ float vs[6*FDIM];
  int t = threadIdx.x;
  for (int i=t; i<6*FDIM; i+=256) vs[i] = vvb[i];
  __syncthreads();
  int g = blockIdx.x*256 + t;
  int w = g >> 6, lane = g & 63;
  if (w >= MM_) return;
  const float* r = hattr + (size_t)w*FDIM;
  double s[6] = {0,0,0,0,0,0};
#pragma unroll
  for (int c=lane; c<FDIM; c+=64){
    double xv = (double)r[c];
#pragma unroll
    for (int q=0;q<6;++q) s[q] = fma(xv, (double)vs[q*FDIM + c], s[q]);
  }
#pragma unroll
  for (int q=0;q<6;++q){
    double v = s[q];
    for (int ofs=32; ofs; ofs>>=1) v += __shfl_down(v, ofs);
    if (lane==0) s2all[(size_t)q*MM_ + w] = (float)v;
  }
}

// ---------------- fused alpha: single pass; writes PACKED {row, alpha} metas ----------------
// an2[i]  = {eilb[i], dinv*alpha}  (node order, for out_s)
// ah2[pp] = {w,       alpha}       (hyperedge order, for m_s; gathered row IS the node w)
__global__ __launch_bounds__(256)
void node_alpha_b(const int* __restrict__ stb_, const int* __restrict__ eilb,
                  const int* __restrict__ enpb, const float* __restrict__ xlb,
                  const float* __restrict__ atts, const float* __restrict__ s2b,
                  const float* __restrict__ dinvb,
                  int2* __restrict__ an2, int2* __restrict__ ah2)
{
  int g = blockIdx.x*256 + threadIdx.x;
  int w = g >> 6, lane = g & 63, k = blockIdx.y;
  if (w >= NN_) return;
  const float* r = xlb + (size_t)k*NN_*FDIM + (size_t)w*FDIM;
  const float* attA = atts + (size_t)k*2*FDIM;
  double s = 0.0;
#pragma unroll
  for (int c=lane; c<FDIM; c+=64) s = fma((double)r[c], (double)attA[c], s);
  for (int ofs=32; ofs; ofs>>=1) s += __shfl_down(s, ofs);
  s = __shfl(s, 0);
  float s1n = (float)s;

  const int* st = stb_ + stBase(k);
  int lo = st[w], hi = st[w+1], len = hi - lo;
  const int* eo = eilb + (size_t)k*E_INC;
  const int* po = enpb + (size_t)k*E_INC;
  const float* s2 = s2b + (size_t)k*MM_;
  float dv = dinvb[(size_t)k*NN_ + w];
  int2* alo = an2 + (size_t)k*E_INC;
  int2* ahi = ah2 + (size_t)k*E_INC;

  if (len <= 64){
    int i = lo + lane;
    bool active = lane < len;
    int m  = active ? eo[i] : 0;
    int pp = active ? po[i] : 0;
    float a = active ? lrelu(s1n + s2[m]) : -INFINITY;
    float mx = a;
    for (int ofs=32; ofs; ofs>>=1) mx = fmaxf(mx, __shfl_xor(mx, ofs));
    if (len == 0) mx = 0.0f;
    float e = active ? expf(a - mx) : 0.0f;
    double se = (double)e;
    for (int ofs=32; ofs; ofs>>=1) se += __shfl_xor(se, ofs);
    float sumf = (float)se;
    if (active){
      float v = e / sumf;
      alo[i] = make_int2(m, __float_as_int(__fmul_rn(dv, v)));
      ahi[pp] = make_int2(w, __float_as_int(v));
    }
  } else {
    float mx = -INFINITY;
    for (int i=lo+lane; i<hi; i+=64) mx = fmaxf(mx, lrelu(s1n + s2[eo[i]]));
    for (int ofs=32; ofs; ofs>>=1) mx = fmaxf(mx, __shfl_xor(mx, ofs));
    double se = 0.0;
    for (int i=lo+lane; i<hi; i+=64){
      float a = lrelu(s1n + s2[eo[i]]);
      se += (double)expf(a - mx);
    }
    for (int ofs=32; ofs; ofs>>=1) se += __shfl_xor(se, ofs);
    float sumf = (float)se;
    for (int i=lo+lane; i<hi; i+=64){
      float a = lrelu(s1n + s2[eo[i]]);
      float v = expf(a - mx) / sumf;
      alo[i] = make_int2(eo[i], __float_as_int(__fmul_rn(dv, v)));
      ahi[po[i]] = make_int2(w, __float_as_int(v));
    }
  }
}

// ---------------- propagation: col-slice x XCD-pinned, packed meta, length-balanced ----------------
// Wave = 8 buckets x one 32-col slice (8 lanes/bucket, float4/lane).
// slice = blockIdx%8 -> XCD pin; bucket ids come from length-sorted perm -> minimal divergence.
// Per-bucket accumulation: sequential ascending i -> bit-identical to prior rounds.
__global__ __launch_bounds__(256)
void m_s(const int* __restrict__ stb_, const int* __restrict__ eperm,
         const int2* __restrict__ ah2, const float* __restrict__ xlb,
         float* __restrict__ mball)
{
  int b = blockIdx.x;
  int k = b >> 12;                 // branch: 4096 blocks each
  int bb = b & 4095;
  int slice = bb & 7;
  int grp = bb >> 3;               // 0..511 (32 edges per block)
  int t = threadIdx.x;
  int lane = t & 63;
  int slot = grp*32 + (t>>6)*8 + (lane>>3);
  int w = eperm[(size_t)k*MM_ + slot];     // hyperedge id (length-balanced)
  int c = lane & 7;
  const int* st = stb_ + stBase(3+k);
  int lo = st[w], hi = st[w+1];
  float binv = (hi > lo) ? 1.0f/(float)(hi-lo) : 0.0f;
  const int2* mh = ah2 + (size_t)k*E_INC;
  const float* tab = xlb + (size_t)k*NN_*FDIM;
  int col = (slice<<5) + (c<<2);
  float ax=0.f, ay=0.f, az=0.f, aw=0.f;
#pragma unroll 4
  for (int i=lo; i<hi; ++i){
    int2 p = mh[i];
    float cv = __fmul_rn(binv, __int_as_float(p.y));
    float4 v = *(const float4*)(tab + (size_t)p.x*FDIM + col);
    ax = __fadd_rn(ax, __fmul_rn(cv, v.x));
    ay = __fadd_rn(ay, __fmul_rn(cv, v.y));
    az = __fadd_rn(az, __fmul_rn(cv, v.z));
    aw = __fadd_rn(aw, __fmul_rn(cv, v.w));
  }
  *(float4*)(mball + (size_t)k*MM_*FDIM + (size_t)w*FDIM + col) = make_float4(ax,ay,az,aw);
}

__global__ __launch_bounds__(256)
void out_s(const int* __restrict__ stb_, const int* __restrict__ nperm,
           const int2* __restrict__ an2, const float* __restrict__ mball,
           const float* __restrict__ bcs, float* __restrict__ ob)
{
  int b = blockIdx.x;
  int k = b / 3072;                // branch: 3072 blocks each
  int bb = b - k*3072;
  int slice = bb & 7;
  int grp = bb >> 3;               // 0..383 (32 nodes per block)
  int t = threadIdx.x;
  int lane = t & 63;
  int slot = grp*32 + (t>>6)*8 + (lane>>3);
  int w = nperm[(size_t)k*NN_ + slot];     // node id (length-balanced)
  int c = lane & 7;
  const int* st = stb_ + stBase(k);
  int lo = st[w], hi = st[w+1];
  const int2* mh = an2 + (size_t)k*E_INC;
  const float* tab = mball + (size_t)k*MM_*FDIM;
  int col = (slice<<5) + (c<<2);
  float ax=0.f, ay=0.f, az=0.f, aw=0.f;
#pragma unroll 4
  for (int i=lo; i<hi; ++i){
    int2 p = mh[i];
    float cv = __int_as_float(p.y);          // already dinv-scaled
    float4 v = *(const float4*)(tab + (size_t)p.x*FDIM + col);
    ax = __fadd_rn(ax, __fmul_rn(cv, v.x));
    ay = __fadd_rn(ay, __fmul_rn(cv, v.y));
    az = __fadd_rn(az, __fmul_rn(cv, v.z));
    aw = __fadd_rn(aw, __fmul_rn(cv, v.w));
  }
  const float4 b4 = *(const float4*)(bcs + (size_t)k*FDIM + col);
  ax = __fadd_rn(ax, b4.x); ay = __fadd_rn(ay, b4.y);
  az = __fadd_rn(az, b4.z); aw = __fadd_rn(aw, b4.w);
  *(float4*)(ob + (size_t)k*NN_*FDIM + (size_t)w*FDIM + col) = make_float4(ax,ay,az,aw);
}

// combine: h = lrelu((o0 + o1) + o2) -- identical accumulate order to sequential path
__global__ __launch_bounds__(256)
void combine_k(const float* __restrict__ ob, float* __restrict__ acc,
               float* __restrict__ mirror)
{
  int i = blockIdx.x*256 + threadIdx.x;           // float4 index
  const int TOT = NN_*FDIM/4;
  if (i >= TOT) return;
  const float4* o0 = (const float4*)ob;
  const float4* o1 = o0 + TOT;
  const float4* o2 = o1 + TOT;
  float4 a = o0[i], b = o1[i], c = o2[i];
  float4 r;
  r.x = lrelu(__fadd_rn(__fadd_rn(a.x, b.x), c.x));
  r.y = lrelu(__fadd_rn(__fadd_rn(a.y, b.y), c.y));
  r.z = lrelu(__fadd_rn(__fadd_rn(a.z, b.z), c.z));
  r.w = lrelu(__fadd_rn(__fadd_rn(a.w, b.w), c.w));
  ((float4*)acc)[i] = r;
  if (mirror) ((float4*)mirror)[i] = r;
}

// ---------------- host orchestration ----------------
extern "C" void kernel_launch(void* const* d_in, const int* in_sizes, int n_in,
                              void* d_out, int out_size, void* d_ws, size_t ws_size,
                              hipStream_t stream)
{
  (void)in_sizes; (void)n_in; (void)out_size; (void)ws_size;
  const float* g     = (const float*)d_in[0];
  const float* x     = (const float*)d_in[1];
  const float* hw    = (const float*)d_in[2];
  const float* hattr = (const float*)d_in[3];
  const int* ni[3]   = {(const int*)d_in[4], (const int*)d_in[6], (const int*)d_in[8]};
  const int* ei[3]   = {(const int*)d_in[5], (const int*)d_in[7], (const int*)d_in[9]};
  const float* W0  = (const float*)d_in[10];
  const float* b0  = (const float*)d_in[11];
  const float* Wh1 = (const float*)d_in[12];
  const float* att1= (const float*)d_in[13];
  const float* bc1 = (const float*)d_in[14];
  const float* W1  = (const float*)d_in[15];
  const float* b1  = (const float*)d_in[16];
  const float* Wh2 = (const float*)d_in[17];
  const float* att2= (const float*)d_in[18];
  const float* bc2 = (const float*)d_in[19];
  const float* Wg  = (const float*)d_in[20];
  const float* bg  = (const float*)d_in[21];
  const float* Wx  = (const float*)d_in[22];
  const float* bx  = (const float*)d_in[23];
  float* outp = (float*)d_out;

  char* base = (char*)d_ws;
  size_t off = 0;
  auto alloc = [&](size_t bytes)->void*{
    void* p = base + off;
    off = (off + bytes + 255) & ~(size_t)255;
    return p;
  };
  const size_t SZ_H = (size_t)NN_*FDIM;
  float* hA    = (float*)alloc(SZ_H*4);
  float* acc   = (float*)alloc(SZ_H*4);
  float* xlb   = (float*)alloc(3*SZ_H*4);
  float* mball = (float*)alloc((size_t)3*MM_*FDIM*4);   // aliased as pbuf during CSR build
  float* ob    = (float*)alloc(3*SZ_H*4);               // aliased as eposb during aux build
  int2*  an2   = (int2*)alloc((size_t)3*E_INC*8);
  int2*  ah2   = (int2*)alloc((size_t)3*E_INC*8);
  float* vvb   = (float*)alloc((size_t)6*FDIM*4);
  float* s2all = (float*)alloc((size_t)6*MM_*4);
  float* dinvb = (float*)alloc((size_t)3*NN_*4);
  float* ngbuf = (float*)alloc((size_t)8192*CDIM*4);
  float* xs1   = (float*)alloc((size_t)4096*CDIM*4);
  float* xs2   = (float*)alloc((size_t)4096*CDIM*4);
  int*   ccnt  = (int*)alloc((size_t)6*PKEYS*4);
  int*   ccur  = (int*)alloc((size_t)6*PKEYS*4);
  int*   cstart= (int*)alloc((size_t)6*129*4);
  int*   stb   = (int*)alloc((size_t)(3*(NN_+1)+3*(MM_+1))*4);
  int*   lists = (int*)alloc((size_t)6*E_INC*4);
  int*   eilb  = (int*)alloc((size_t)3*E_INC*4);
  int*   enpb  = (int*)alloc((size_t)3*E_INC*4);
  int*   nperm = (int*)alloc((size_t)3*NN_*4);
  int*   eperm = (int*)alloc((size_t)3*MM_*4);
  int*   pbuf  = (int*)mball;   // CSR scratch, dead before mball first written
  int*   eposb = (int*)ob;      // aux scratch, dead before ob first written

  // ---- CSR build (shared by both hyper layers) ----
  hipMemsetAsync(ccnt, 0, (size_t)6*PKEYS*4, stream);
  Ptrs6 ip{{ni[0],ni[1],ni[2],ei[0],ei[1],ei[2]}};
  coarse_hist <<<dim3(96,6),256,0,stream>>>(ip, ccnt);
  coarse_scan <<<6,128,0,stream>>>(ccnt, cstart, ccur);
  part_scatter<<<dim3(96,6),256,0,stream>>>(ip, ccur, pbuf);
  fine_build  <<<dim3(128,6),256,0,stream>>>(ip, cstart, pbuf, stb, lists);
  sortb_kernel<<<dim3(4096,6),256,0,stream>>>(stb, lists);

  // ---- resolve loop-invariant indirections once ----
  AuxH ahp{{lists + (size_t)3*E_INC, lists + (size_t)4*E_INC, lists + (size_t)5*E_INC}};
  aux_h<<<dim3(E_INC/256,3),256,0,stream>>>(ahp, eposb);
  AuxN anp{{lists + (size_t)0*E_INC, lists + (size_t)1*E_INC, lists + (size_t)2*E_INC},
           {ei[0], ei[1], ei[2]}};
  aux_n<<<dim3(3072,3),256,0,stream>>>(anp, stb, eposb, hw, eilb, enpb, dinvb);
  perm_build<<<6,256,0,stream>>>(stb, nperm, eperm);

  // ---- h-independent attention scalars: all 6 (layer,branch) configs ----
  vv_all<<<384,256,0,stream>>>(Wh1, Wh2, att1, att2, vvb);
  s2_all<<<4096,256,0,stream>>>(hattr, vvb, s2all);

  // ---- layer0 ----
  gemm_nn<<<dim3(192,4),256,0,stream>>>(g, W0, b0, hA, FDIM, 12, 1);

  auto hyper = [&](int layer, const float* hin, const float* Whs, const float* atts,
                   const float* bcs, float* mirror){
    gemm_nn3<<<dim3(192,4,3),256,0,stream>>>(hin, Whs, xlb);
    node_alpha_b<<<dim3(3072,3),256,0,stream>>>(stb, eilb, enpb, xlb, atts,
                                                s2all + (size_t)layer*3*MM_, dinvb, an2, ah2);
    m_s  <<<12288,256,0,stream>>>(stb, eperm, ah2, xlb, mball);
    out_s<<<9216,256,0,stream>>>(stb, nperm, an2, mball, bcs, ob);
    combine_k<<<3072,256,0,stream>>>(ob, acc, mirror);
  };

  hyper(0, hA, Wh1, att1, bc1, nullptr);
  gemm_nn<<<dim3(192,4),256,0,stream>>>(acc, W1, b1, hA, FDIM, 12, 1);
  hyper(1, hA, Wh2, att2, bc2, outp + (size_t)4096*8192);  // mirrors final h to output

  // ---- projections: ng1|ng2 in one segmented launch; xs1,xs2 ----
  gemm_nn<<<dim3(128,2),256,0,stream>>>(acc + (size_t)4096*FDIM, Wg + (size_t)FDIM*CDIM,
                                        bg + CDIM, ngbuf, CDIM, 12, 1);
  gemm_nn<<<dim3(64,2),256,0,stream>>>(x, Wx + (size_t)1*FDIM*CDIM, bx + 1*CDIM, xs1, CDIM, 30, 1);
  gemm_nn<<<dim3(64,2),256,0,stream>>>(x, Wx + (size_t)2*FDIM*CDIM, bx + 2*CDIM, xs2, CDIM, 30, 1);

  // ---- result = [xs1 @ ng1^T , xs2 @ ng2^T]  (4096 x 8192) ----
  gemm_nt<<<dim3(32,32),256,0,stream>>>(xs1, ngbuf, outp, 8192, 0);
  gemm_nt<<<dim3(32,32),256,0,stream>>>(xs2, ngbuf + (size_t)4096*CDIM, outp, 8192, 4096);
}

// Round 7
// 1024.073 us; speedup vs baseline: 1.1133x; 1.1133x over previous
//
#include <hip/hip_runtime.h>
#include <cmath>

#define E_INC   393216
#define NN_     12288
#define MM_     16384
#define FDIM    256
#define CDIM    128
#define PKEYS   128
#define LCAP    6144

__host__ __device__ inline int stBase(int r){ return r<3 ? r*(NN_+1) : 3*(NN_+1) + (r-3)*(MM_+1); }
__host__ __device__ inline int nParts(int r){ return (r<3 ? NN_ : MM_) / PKEYS; }  // 96 or 128

__device__ __forceinline__ float lrelu(float v){ return v >= 0.0f ? v : 0.2f*v; }

struct Ptrs6 { const int* p[6]; };

// ---------------- CSR build: two-level partition (write-locality) ----------------
__global__ __launch_bounds__(256) void coarse_hist(Ptrs6 keys, int* __restrict__ ccnt){
  __shared__ int h[PKEYS];
  int r = blockIdx.y, t = threadIdx.x;
  if (t < PKEYS) h[t] = 0;
  __syncthreads();
  int base = blockIdx.x * 4096;
  const int* ka = keys.p[r];
  for (int j=0;j<16;++j) atomicAdd(&h[ka[base + j*256 + t] >> 7], 1);
  __syncthreads();
  if (t < PKEYS) atomicAdd(&ccnt[r*PKEYS + t], h[t]);
}

__global__ __launch_bounds__(128) void coarse_scan(const int* __restrict__ ccnt,
                                                   int* __restrict__ cstart,
                                                   int* __restrict__ ccur){
  int r = blockIdx.x, t = threadIdx.x;
  int P = nParts(r);
  int c = (t < P) ? ccnt[r*PKEYS + t] : 0;
  __shared__ int sd[128];
  sd[t] = c; __syncthreads();
  for (int ofs=1; ofs<128; ofs<<=1){
    int v = (t>=ofs) ? sd[t-ofs] : 0;
    __syncthreads(); sd[t] += v; __syncthreads();
  }
  int excl = sd[t] - c;
  cstart[r*129 + t] = excl;
  ccur[r*PKEYS + t] = excl;
  if (t == 127) cstart[r*129 + 128] = sd[127];
}

__global__ __launch_bounds__(256) void part_scatter(Ptrs6 keys, int* __restrict__ ccur,
                                                    int* __restrict__ pbuf){
  __shared__ int h[PKEYS];
  __shared__ int cur[PKEYS];
  int r = blockIdx.y, t = threadIdx.x;
  if (t < PKEYS) h[t] = 0;
  __syncthreads();
  int base = blockIdx.x * 4096;
  const int* ka = keys.p[r];
  int myk[16];
  for (int j=0;j<16;++j){
    myk[j] = ka[base + j*256 + t] >> 7;
    atomicAdd(&h[myk[j]], 1);
  }
  __syncthreads();
  if (t < PKEYS) cur[t] = atomicAdd(&ccur[r*PKEYS + t], h[t]);
  __syncthreads();
  int* pb = pbuf + (size_t)r * E_INC;
  for (int j=0;j<16;++j){
    int pos = atomicAdd(&cur[myk[j]], 1);
    pb[pos] = base + j*256 + t;
  }
}

__global__ __launch_bounds__(256) void fine_build(Ptrs6 keys, const int* __restrict__ cstart,
                                                  const int* __restrict__ pbuf,
                                                  int* __restrict__ starts,
                                                  int* __restrict__ lists){
  __shared__ unsigned short kb[LCAP];
  __shared__ int ob[LCAP];
  __shared__ int h[PKEYS], ls[PKEYS], lc[PKEYS];
  int r = blockIdx.y, p = blockIdx.x, t = threadIdx.x;
  int P = nParts(r);
  if (p >= P) return;
  int lo = cstart[r*129 + p], hi = cstart[r*129 + p + 1];
  int len = hi - lo;
  if (t < PKEYS) h[t] = 0;
  __syncthreads();
  const int* ka = keys.p[r];
  const int* pb = pbuf + (size_t)r * E_INC;
  int* lst = lists + (size_t)r * E_INC;
  int kbase = p << 7;
  int sb = stBase(r);
  if (len <= LCAP){
    for (int i=t; i<len; i+=256){
      int e = pb[lo+i];
      int k = ka[e] - kbase;
      kb[i] = (unsigned short)k;
      atomicAdd(&h[k], 1);
    }
    __syncthreads();
    if (t == 0){ int run = 0; for (int k=0;k<PKEYS;++k){ ls[k]=run; lc[k]=run; run+=h[k]; } }
    __syncthreads();
    for (int i=t; i<len; i+=256){
      int pos = atomicAdd(&lc[kb[i]], 1);
      ob[pos] = pb[lo+i];
    }
    __syncthreads();
    for (int i=t; i<len; i+=256) lst[lo+i] = ob[i];
    if (t < PKEYS) starts[sb + kbase + t] = lo + ls[t];
  } else {
    for (int i=t; i<len; i+=256) atomicAdd(&h[ka[pb[lo+i]] - kbase], 1);
    __syncthreads();
    if (t == 0){ int run = 0; for (int k=0;k<PKEYS;++k){ ls[k]=run; lc[k]=run; run+=h[k]; } }
    __syncthreads();
    for (int i=t; i<len; i+=256){
      int e = pb[lo+i];
      int pos = atomicAdd(&lc[ka[e] - kbase], 1);
      lst[lo+pos] = e;
    }
    if (t < PKEYS) starts[sb + kbase + t] = lo + ls[t];
  }
  if (p == P-1 && t == 0) starts[sb + (r<3 ? NN_ : MM_)] = hi;
}

// sort each bucket ascending -> accumulation order == numpy sequential order.
__global__ __launch_bounds__(256) void sortb_kernel(const int* __restrict__ starts,
                                                    int* __restrict__ lists){
  int r = blockIdx.y;
  int nb = (r<3) ? NN_ : MM_;
  int wid = (blockIdx.x*256 + threadIdx.x) >> 6;
  int lane = threadIdx.x & 63;
  if (wid >= nb) return;
  int sb = stBase(r);
  int lo = starts[sb+wid], hi = starts[sb+wid+1];
  int len = hi - lo;
  if (len <= 1) return;
  int* lst = lists + (size_t)r*E_INC;
  if (len <= 64){
    int v = (lane < len) ? lst[lo+lane] : 0x7fffffff;
#pragma unroll
    for (int k = 2; k <= 64; k <<= 1){
#pragma unroll
      for (int j = k>>1; j > 0; j >>= 1){
        int o = __shfl_xor(v, j);
        bool up    = ((lane & k) == 0);
        bool lower = ((lane & j) == 0);
        int mn = min(v,o), mx = max(v,o);
        v = (lower == up) ? mn : mx;
      }
    }
    if (lane < len) lst[lo+lane] = v;
  } else if (lane == 0) {
    for (int i=lo+1; i<hi; ++i){
      int key = lst[i]; int j = i-1;
      while (j>=lo && lst[j]>key){ lst[j+1]=lst[j]; --j; }
      lst[j+1]=key;
    }
  }
}

// ---------------- build-time index resolution (loop-invariant across layers) ----------------
struct AuxH { const int* el[3]; };
__global__ __launch_bounds__(256) void aux_h(AuxH a, int* __restrict__ eposb){
  int k = blockIdx.y;
  int i = blockIdx.x*256 + threadIdx.x;
  int e = a.el[k][i];
  eposb[(size_t)k*E_INC + e] = i;
}

struct AuxN { const int* nl[3]; const int* ei[3]; };
__global__ __launch_bounds__(256) void aux_n(AuxN a, const int* __restrict__ stb_,
                                             const int* __restrict__ eposb,
                                             const float* __restrict__ hw,
                                             int* __restrict__ eilb, int* __restrict__ enpb,
                                             float* __restrict__ dinvb){
  int g = blockIdx.x*256 + threadIdx.x;
  int w = g >> 6, lane = g & 63, k = blockIdx.y;
  if (w >= NN_) return;
  const int* st = stb_ + stBase(k);
  int lo = st[w], hi = st[w+1];
  const int* nl = a.nl[k];
  const int* ei = a.ei[k];
  const int* ep = eposb + (size_t)k*E_INC;
  int* eo = eilb + (size_t)k*E_INC;
  int* po = enpb + (size_t)k*E_INC;
  double sd = 0.0;
  for (int i=lo+lane; i<hi; i+=64){
    int e = nl[i]; int m = ei[e];
    eo[i] = m; po[i] = ep[e];
    sd += (double)hw[m];
  }
  for (int ofs=32; ofs; ofs>>=1) sd += __shfl_xor(sd, ofs);
  if (lane==0){
    float D = (float)sd;
    dinvb[(size_t)k*NN_ + w] = (D > 0.0f) ? 1.0f/D : 0.0f;
  }
}

// ---------------- fp32 GEMMs ----------------
__global__ __launch_bounds__(256)
void gemm_nn(const float* __restrict__ A, const float* __restrict__ W,
             const float* __restrict__ bias, float* __restrict__ C,
             int N, int segShift, int act)
{
  __shared__ alignas(16) float As[16][72];
  __shared__ alignas(16) float Bs[16][72];
  int t = threadIdx.x;
  int bm = blockIdx.x * 64;
  int bn = blockIdx.y * 64;
  int seg = bm >> segShift;
  const float* Wp = W + (size_t)seg * FDIM * N;
  int tx = t & 15, ty = t >> 4;
  int arow = t >> 2, acq = (t & 3) << 2;
  int brow = t >> 4, bcol = (t & 15) << 2;

  float acc[4][4] = {};
  for (int k0 = 0; k0 < FDIM; k0 += 16){
    float4 a0 = *(const float4*)(A + (size_t)(bm+arow)*FDIM + k0 + acq);
    As[acq+0][arow]=a0.x; As[acq+1][arow]=a0.y; As[acq+2][arow]=a0.z; As[acq+3][arow]=a0.w;
    *(float4*)&Bs[brow][bcol] = *(const float4*)(Wp + (size_t)(k0+brow)*N + bn + bcol);
    __syncthreads();
#pragma unroll
    for (int kk=0; kk<16; ++kk){
      float4 av = *(const float4*)&As[kk][ty<<2];
      float4 bv = *(const float4*)&Bs[kk][tx<<2];
      float af[4] = {av.x,av.y,av.z,av.w};
      float bf[4] = {bv.x,bv.y,bv.z,bv.w};
#pragma unroll
      for (int i=0;i<4;++i)
#pragma unroll
        for (int j=0;j<4;++j) acc[i][j] = fmaf(af[i], bf[j], acc[i][j]);
    }
    __syncthreads();
  }
  int c0 = bn + (tx<<2);
  float4 bb = make_float4(0.f,0.f,0.f,0.f);
  if (bias) bb = *(const float4*)(bias + (size_t)seg*N + c0);
#pragma unroll
  for (int i=0;i<4;++i){
    float4 o = make_float4(acc[i][0],acc[i][1],acc[i][2],acc[i][3]);
    if (bias){ o.x+=bb.x; o.y+=bb.y; o.z+=bb.z; o.w+=bb.w; }
    if (act){ o.x=lrelu(o.x); o.y=lrelu(o.y); o.z=lrelu(o.z); o.w=lrelu(o.w); }
    *(float4*)(C + (size_t)(bm+(ty<<2)+i)*N + c0) = o;
  }
}

// 3-branch xl GEMM: C[z] = A @ W[z]; identical tiling/math to gemm_nn (N=FDIM, no bias/act)
__global__ __launch_bounds__(256)
void gemm_nn3(const float* __restrict__ A, const float* __restrict__ Wall,
              float* __restrict__ Call)
{
  __shared__ alignas(16) float As[16][72];
  __shared__ alignas(16) float Bs[16][72];
  int t = threadIdx.x;
  int bm = blockIdx.x * 64;
  int bn = blockIdx.y * 64;
  int z = blockIdx.z;
  const float* Wp = Wall + (size_t)z * FDIM * FDIM;
  float* C = Call + (size_t)z * NN_ * FDIM;
  int tx = t & 15, ty = t >> 4;
  int arow = t >> 2, acq = (t & 3) << 2;
  int brow = t >> 4, bcol = (t & 15) << 2;

  float acc[4][4] = {};
  for (int k0 = 0; k0 < FDIM; k0 += 16){
    float4 a0 = *(const float4*)(A + (size_t)(bm+arow)*FDIM + k0 + acq);
    As[acq+0][arow]=a0.x; As[acq+1][arow]=a0.y; As[acq+2][arow]=a0.z; As[acq+3][arow]=a0.w;
    *(float4*)&Bs[brow][bcol] = *(const float4*)(Wp + (size_t)(k0+brow)*FDIM + bn + bcol);
    __syncthreads();
#pragma unroll
    for (int kk=0; kk<16; ++kk){
      float4 av = *(const float4*)&As[kk][ty<<2];
      float4 bv = *(const float4*)&Bs[kk][tx<<2];
      float af[4] = {av.x,av.y,av.z,av.w};
      float bf[4] = {bv.x,bv.y,bv.z,bv.w};
#pragma unroll
      for (int i=0;i<4;++i)
#pragma unroll
        for (int j=0;j<4;++j) acc[i][j] = fmaf(af[i], bf[j], acc[i][j]);
    }
    __syncthreads();
  }
  int c0 = bn + (tx<<2);
#pragma unroll
  for (int i=0;i<4;++i){
    float4 o = make_float4(acc[i][0],acc[i][1],acc[i][2],acc[i][3]);
    *(float4*)(C + (size_t)(bm+(ty<<2)+i)*FDIM + c0) = o;
  }
}

__global__ __launch_bounds__(256)
void gemm_nt(const float* __restrict__ A, const float* __restrict__ B,
             float* __restrict__ C, int ldc, int colOff)
{
  __shared__ alignas(16) float As[16][132];
  __shared__ alignas(16) float Bs[16][132];
  int t = threadIdx.x;
  int bm = blockIdx.x * 128;
  int bn = blockIdx.y * 128;
  int tx = t & 15, ty = t >> 4;
  int arow = t >> 1, akq = (t & 1) << 3;

  float acc[8][8] = {};
  for (int k0 = 0; k0 < CDIM; k0 += 16){
    const float* ap = A + (size_t)(bm+arow)*CDIM + k0 + akq;
    float4 a0 = *(const float4*)(ap);
    float4 a1 = *(const float4*)(ap + 4);
    As[akq+0][arow]=a0.x; As[akq+1][arow]=a0.y; As[akq+2][arow]=a0.z; As[akq+3][arow]=a0.w;
    As[akq+4][arow]=a1.x; As[akq+5][arow]=a1.y; As[akq+6][arow]=a1.z; As[akq+7][arow]=a1.w;
    const float* bp = B + (size_t)(bn+arow)*CDIM + k0 + akq;
    float4 b0 = *(const float4*)(bp);
    float4 b1 = *(const float4*)(bp + 4);
    Bs[akq+0][arow]=b0.x; Bs[akq+1][arow]=b0.y; Bs[akq+2][arow]=b0.z; Bs[akq+3][arow]=b0.w;
    Bs[akq+4][arow]=b1.x; Bs[akq+5][arow]=b1.y; Bs[akq+6][arow]=b1.z; Bs[akq+7][arow]=b1.w;
    __syncthreads();
#pragma unroll
    for (int kk=0; kk<16; ++kk){
      float4 x0 = *(const float4*)&As[kk][ty<<3];
      float4 x1 = *(const float4*)&As[kk][(ty<<3)+4];
      float4 y0 = *(const float4*)&Bs[kk][tx<<3];
      float4 y1 = *(const float4*)&Bs[kk][(tx<<3)+4];
      float af[8] = {x0.x,x0.y,x0.z,x0.w,x1.x,x1.y,x1.z,x1.w};
      float bf[8] = {y0.x,y0.y,y0.z,y0.w,y1.x,y1.y,y1.z,y1.w};
#pragma unroll
      for (int i=0;i<8;++i)
#pragma unroll
        for (int j=0;j<8;++j) acc[i][j] = fmaf(af[i], bf[j], acc[i][j]);
    }
    __syncthreads();
  }
  int c0 = colOff + bn + (tx<<3);
#pragma unroll
  for (int i=0;i<8;++i){
    float* cp = C + (size_t)(bm+(ty<<3)+i)*ldc + c0;
    *(float4*)(cp)   = make_float4(acc[i][0],acc[i][1],acc[i][2],acc[i][3]);
    *(float4*)(cp+4) = make_float4(acc[i][4],acc[i][5],acc[i][6],acc[i][7]);
  }
}

// ---------------- attention scalars (hoisted + fused) ----------------
__global__ __launch_bounds__(256)
void vv_all(const float* __restrict__ Wh1, const float* __restrict__ Wh2,
            const float* __restrict__ att1, const float* __restrict__ att2,
            float* __restrict__ vvb)
{
  int g = blockIdx.x*256 + threadIdx.x;
  int w = g >> 6, lane = g & 63;
  if (w >= 6*FDIM) return;
  int cfg = w >> 8, rr = w & 255;
  int l = cfg / 3, k = cfg % 3;
  const float* r = (l ? Wh2 : Wh1) + (size_t)k*FDIM*FDIM + (size_t)rr*FDIM;
  const float* vec = (l ? att2 : att1) + (size_t)k*2*FDIM + FDIM;
  double s = 0.0;
#pragma unroll
  for (int c=lane; c<FDIM; c+=64) s = fma((double)r[c], (double)vec[c], s);
  for (int ofs=32; ofs; ofs>>=1) s += __shfl_down(s, ofs);
  if (lane==0) vvb[cfg*FDIM + rr] = (float)s;
}

__global__ __launch_bounds__(256)
void s2_all(const float* __restrict__ hattr, const float* __restrict__ vvb,
            float* __restrict__ s2all)
{
  __shared__ float vs[6*FDIM];
  int t = threadIdx.x;
  for (int i=t; i<6*FDIM; i+=256) vs[i] = vvb[i];
  __syncthreads();
  int g = blockIdx.x*256 + t;
  int w = g >> 6, lane = g & 63;
  if (w >= MM_) return;
  const float* r = hattr + (size_t)w*FDIM;
  double s[6] = {0,0,0,0,0,0};
#pragma unroll
  for (int c=lane; c<FDIM; c+=64){
    double xv = (double)r[c];
#pragma unroll
    for (int q=0;q<6;++q) s[q] = fma(xv, (double)vs[q*FDIM + c], s[q]);
  }
#pragma unroll
  for (int q=0;q<6;++q){
    double v = s[q];
    for (int ofs=32; ofs; ofs>>=1) v += __shfl_down(v, ofs);
    if (lane==0) s2all[(size_t)q*MM_ + w] = (float)v;
  }
}

// ---------------- fused alpha: single pass; writes PACKED {row, alpha} metas ----------------
// an2[i]  = {eilb[i], dinv*alpha}  (node order, for out_s)
// ah2[pp] = {w,       alpha}       (hyperedge order, for m_s; gathered row IS the node w)
__global__ __launch_bounds__(256)
void node_alpha_b(const int* __restrict__ stb_, const int* __restrict__ eilb,
                  const int* __restrict__ enpb, const float* __restrict__ xlb,
                  const float* __restrict__ atts, const float* __restrict__ s2b,
                  const float* __restrict__ dinvb,
                  int2* __restrict__ an2, int2* __restrict__ ah2)
{
  int g = blockIdx.x*256 + threadIdx.x;
  int w = g >> 6, lane = g & 63, k = blockIdx.y;
  if (w >= NN_) return;
  const float* r = xlb + (size_t)k*NN_*FDIM + (size_t)w*FDIM;
  const float* attA = atts + (size_t)k*2*FDIM;
  double s = 0.0;
#pragma unroll
  for (int c=lane; c<FDIM; c+=64) s = fma((double)r[c], (double)attA[c], s);
  for (int ofs=32; ofs; ofs>>=1) s += __shfl_down(s, ofs);
  s = __shfl(s, 0);
  float s1n = (float)s;

  const int* st = stb_ + stBase(k);
  int lo = st[w], hi = st[w+1], len = hi - lo;
  const int* eo = eilb + (size_t)k*E_INC;
  const int* po = enpb + (size_t)k*E_INC;
  const float* s2 = s2b + (size_t)k*MM_;
  float dv = dinvb[(size_t)k*NN_ + w];
  int2* alo = an2 + (size_t)k*E_INC;
  int2* ahi = ah2 + (size_t)k*E_INC;

  if (len <= 64){
    int i = lo + lane;
    bool active = lane < len;
    int m  = active ? eo[i] : 0;
    int pp = active ? po[i] : 0;
    float a = active ? lrelu(s1n + s2[m]) : -INFINITY;
    float mx = a;
    for (int ofs=32; ofs; ofs>>=1) mx = fmaxf(mx, __shfl_xor(mx, ofs));
    if (len == 0) mx = 0.0f;
    float e = active ? expf(a - mx) : 0.0f;
    double se = (double)e;
    for (int ofs=32; ofs; ofs>>=1) se += __shfl_xor(se, ofs);
    float sumf = (float)se;
    if (active){
      float v = e / sumf;
      alo[i] = make_int2(m, __float_as_int(__fmul_rn(dv, v)));
      ahi[pp] = make_int2(w, __float_as_int(v));
    }
  } else {
    float mx = -INFINITY;
    for (int i=lo+lane; i<hi; i+=64) mx = fmaxf(mx, lrelu(s1n + s2[eo[i]]));
    for (int ofs=32; ofs; ofs>>=1) mx = fmaxf(mx, __shfl_xor(mx, ofs));
    double se = 0.0;
    for (int i=lo+lane; i<hi; i+=64){
      float a = lrelu(s1n + s2[eo[i]]);
      se += (double)expf(a - mx);
    }
    for (int ofs=32; ofs; ofs>>=1) se += __shfl_xor(se, ofs);
    float sumf = (float)se;
    for (int i=lo+lane; i<hi; i+=64){
      float a = lrelu(s1n + s2[eo[i]]);
      float v = expf(a - mx) / sumf;
      alo[i] = make_int2(eo[i], __float_as_int(__fmul_rn(dv, v)));
      ahi[po[i]] = make_int2(w, __float_as_int(v));
    }
  }
}

// ---------------- propagation: col-slice x XCD-pinned; reg-resident meta ----------------
// Wave = 8 buckets x one 32-col slice (8 lanes/bucket, float4/lane).
// Metadata for the whole bucket is preloaded into registers (lane c holds meta[lo+8k+c],
// statically indexed) and broadcast via __shfl -> the gather loads are the ONLY VMEM ops
// in the unrolled loop, so the compiler can keep many gathers in flight (no vmcnt drains).
// Accumulation: ascending i per (bucket,col) -> bit-identical. Buckets >64: rare fallback.
__global__ __launch_bounds__(256)
void m_s(const int* __restrict__ stb_,
         const int2* __restrict__ ah2, const float* __restrict__ xlb,
         float* __restrict__ mball)
{
  int b = blockIdx.x;
  int k = b >> 12;                 // branch: 4096 blocks each
  int bb = b & 4095;
  int slice = bb & 7;
  int grp = bb >> 3;               // 0..511 (32 edges per block)
  int t = threadIdx.x;
  int lane = t & 63;
  int w = grp*32 + (t>>6)*8 + (lane>>3);   // hyperedge id
  int c = lane & 7;
  int srcb = lane & 56;            // group base lane
  const int* st = stb_ + stBase(3+k);
  int lo = st[w], hi = st[w+1];
  float binv = (hi > lo) ? 1.0f/(float)(hi-lo) : 0.0f;
  const int2* mh = ah2 + (size_t)k*E_INC;
  const float* tab = xlb + (size_t)k*NN_*FDIM;
  int col = (slice<<5) + (c<<2);
  int2 mr[8];
#pragma unroll
  for (int kk=0; kk<8; ++kk){
    int idx = lo + (kk<<3) + c;
    mr[kk] = (idx < hi) ? mh[idx] : make_int2(0,0);
  }
  float ax=0.f, ay=0.f, az=0.f, aw=0.f;
#pragma unroll
  for (int kk=0; kk<8; ++kk){
#pragma unroll
    for (int j=0; j<8; ++j){
      int i = lo + (kk<<3) + j;
      if (i < hi){
        int rowi = __shfl(mr[kk].x, srcb | j);
        float cv = __fmul_rn(binv, __int_as_float(__shfl(mr[kk].y, srcb | j)));
        const float4 v = *(const float4*)(tab + (size_t)rowi*FDIM + col);
        ax = __fadd_rn(ax, __fmul_rn(cv, v.x));
        ay = __fadd_rn(ay, __fmul_rn(cv, v.y));
        az = __fadd_rn(az, __fmul_rn(cv, v.z));
        aw = __fadd_rn(aw, __fmul_rn(cv, v.w));
      }
    }
  }
  for (int i = lo+64; i < hi; ++i){        // rare: len > 64
    int2 p = mh[i];
    float cv = __fmul_rn(binv, __int_as_float(p.y));
    const float4 v = *(const float4*)(tab + (size_t)p.x*FDIM + col);
    ax = __fadd_rn(ax, __fmul_rn(cv, v.x));
    ay = __fadd_rn(ay, __fmul_rn(cv, v.y));
    az = __fadd_rn(az, __fmul_rn(cv, v.z));
    aw = __fadd_rn(aw, __fmul_rn(cv, v.w));
  }
  *(float4*)(mball + (size_t)k*MM_*FDIM + (size_t)w*FDIM + col) = make_float4(ax,ay,az,aw);
}

__global__ __launch_bounds__(256)
void out_s(const int* __restrict__ stb_,
           const int2* __restrict__ an2, const float* __restrict__ mball,
           const float* __restrict__ bcs, float* __restrict__ ob)
{
  int b = blockIdx.x;
  int k = b / 3072;                // branch: 3072 blocks each
  int bb = b - k*3072;
  int slice = bb & 7;
  int grp = bb >> 3;               // 0..383 (32 nodes per block)
  int t = threadIdx.x;
  int lane = t & 63;
  int w = grp*32 + (t>>6)*8 + (lane>>3);   // node id
  int c = lane & 7;
  int srcb = lane & 56;
  const int* st = stb_ + stBase(k);
  int lo = st[w], hi = st[w+1];
  const int2* mh = an2 + (size_t)k*E_INC;
  const float* tab = mball + (size_t)k*MM_*FDIM;
  int col = (slice<<5) + (c<<2);
  int2 mr[8];
#pragma unroll
  for (int kk=0; kk<8; ++kk){
    int idx = lo + (kk<<3) + c;
    mr[kk] = (idx < hi) ? mh[idx] : make_int2(0,0);
  }
  float ax=0.f, ay=0.f, az=0.f, aw=0.f;
#pragma unroll
  for (int kk=0; kk<8; ++kk){
#pragma unroll
    for (int j=0; j<8; ++j){
      int i = lo + (kk<<3) + j;
      if (i < hi){
        int rowi = __shfl(mr[kk].x, srcb | j);
        float cv = __int_as_float(__shfl(mr[kk].y, srcb | j));   // dinv-prescaled
        const float4 v = *(const float4*)(tab + (size_t)rowi*FDIM + col);
        ax = __fadd_rn(ax, __fmul_rn(cv, v.x));
        ay = __fadd_rn(ay, __fmul_rn(cv, v.y));
        az = __fadd_rn(az, __fmul_rn(cv, v.z));
        aw = __fadd_rn(aw, __fmul_rn(cv, v.w));
      }
    }
  }
  for (int i = lo+64; i < hi; ++i){        // rare: len > 64
    int2 p = mh[i];
    float cv = __int_as_float(p.y);
    const float4 v = *(const float4*)(tab + (size_t)p.x*FDIM + col);
    ax = __fadd_rn(ax, __fmul_rn(cv, v.x));
    ay = __fadd_rn(ay, __fmul_rn(cv, v.y));
    az = __fadd_rn(az, __fmul_rn(cv, v.z));
    aw = __fadd_rn(aw, __fmul_rn(cv, v.w));
  }
  const float4 b4 = *(const float4*)(bcs + (size_t)k*FDIM + col);
  ax = __fadd_rn(ax, b4.x); ay = __fadd_rn(ay, b4.y);
  az = __fadd_rn(az, b4.z); aw = __fadd_rn(aw, b4.w);
  *(float4*)(ob + (size_t)k*NN_*FDIM + (size_t)w*FDIM + col) = make_float4(ax,ay,az,aw);
}

// combine: h = lrelu((o0 + o1) + o2) -- identical accumulate order to sequential path
__global__ __launch_bounds__(256)
void combine_k(const float* __restrict__ ob, float* __restrict__ acc,
               float* __restrict__ mirror)
{
  int i = blockIdx.x*256 + threadIdx.x;           // float4 index
  const int TOT = NN_*FDIM/4;
  if (i >= TOT) return;
  const float4* o0 = (const float4*)ob;
  const float4* o1 = o0 + TOT;
  const float4* o2 = o1 + TOT;
  float4 a = o0[i], b = o1[i], c = o2[i];
  float4 r;
  r.x = lrelu(__fadd_rn(__fadd_rn(a.x, b.x), c.x));
  r.y = lrelu(__fadd_rn(__fadd_rn(a.y, b.y), c.y));
  r.z = lrelu(__fadd_rn(__fadd_rn(a.z, b.z), c.z));
  r.w = lrelu(__fadd_rn(__fadd_rn(a.w, b.w), c.w));
  ((float4*)acc)[i] = r;
  if (mirror) ((float4*)mirror)[i] = r;
}

// ---------------- host orchestration ----------------
extern "C" void kernel_launch(void* const* d_in, const int* in_sizes, int n_in,
                              void* d_out, int out_size, void* d_ws, size_t ws_size,
                              hipStream_t stream)
{
  (void)in_sizes; (void)n_in; (void)out_size; (void)ws_size;
  const float* g     = (const float*)d_in[0];
  const float* x     = (const float*)d_in[1];
  const float* hw    = (const float*)d_in[2];
  const float* hattr = (const float*)d_in[3];
  const int* ni[3]   = {(const int*)d_in[4], (const int*)d_in[6], (const int*)d_in[8]};
  const int* ei[3]   = {(const int*)d_in[5], (const int*)d_in[7], (const int*)d_in[9]};
  const float* W0  = (const float*)d_in[10];
  const float* b0  = (const float*)d_in[11];
  const float* Wh1 = (const float*)d_in[12];
  const float* att1= (const float*)d_in[13];
  const float* bc1 = (const float*)d_in[14];
  const float* W1  = (const float*)d_in[15];
  const float* b1  = (const float*)d_in[16];
  const float* Wh2 = (const float*)d_in[17];
  const float* att2= (const float*)d_in[18];
  const float* bc2 = (const float*)d_in[19];
  const float* Wg  = (const float*)d_in[20];
  const float* bg  = (const float*)d_in[21];
  const float* Wx  = (const float*)d_in[22];
  const float* bx  = (const float*)d_in[23];
  float* outp = (float*)d_out;

  char* base = (char*)d_ws;
  size_t off = 0;
  auto alloc = [&](size_t bytes)->void*{
    void* p = base + off;
    off = (off + bytes + 255) & ~(size_t)255;
    return p;
  };
  const size_t SZ_H = (size_t)NN_*FDIM;
  float* hA    = (float*)alloc(SZ_H*4);
  float* acc   = (float*)alloc(SZ_H*4);
  float* xlb   = (float*)alloc(3*SZ_H*4);
  float* mball = (float*)alloc((size_t)3*MM_*FDIM*4);   // aliased as pbuf during CSR build
  float* ob    = (float*)alloc(3*SZ_H*4);               // aliased as eposb during aux build
  int2*  an2   = (int2*)alloc((size_t)3*E_INC*8);
  int2*  ah2   = (int2*)alloc((size_t)3*E_INC*8);
  float* vvb   = (float*)alloc((size_t)6*FDIM*4);
  float* s2all = (float*)alloc((size_t)6*MM_*4);
  float* dinvb = (float*)alloc((size_t)3*NN_*4);
  float* ngbuf = (float*)alloc((size_t)8192*CDIM*4);
  float* xs1   = (float*)alloc((size_t)4096*CDIM*4);
  float* xs2   = (float*)alloc((size_t)4096*CDIM*4);
  int*   ccnt  = (int*)alloc((size_t)6*PKEYS*4);
  int*   ccur  = (int*)alloc((size_t)6*PKEYS*4);
  int*   cstart= (int*)alloc((size_t)6*129*4);
  int*   stb   = (int*)alloc((size_t)(3*(NN_+1)+3*(MM_+1))*4);
  int*   lists = (int*)alloc((size_t)6*E_INC*4);
  int*   eilb  = (int*)alloc((size_t)3*E_INC*4);
  int*   enpb  = (int*)alloc((size_t)3*E_INC*4);
  int*   pbuf  = (int*)mball;   // CSR scratch, dead before mball first written
  int*   eposb = (int*)ob;      // aux scratch, dead before ob first written

  // ---- CSR build (shared by both hyper layers) ----
  hipMemsetAsync(ccnt, 0, (size_t)6*PKEYS*4, stream);
  Ptrs6 ip{{ni[0],ni[1],ni[2],ei[0],ei[1],ei[2]}};
  coarse_hist <<<dim3(96,6),256,0,stream>>>(ip, ccnt);
  coarse_scan <<<6,128,0,stream>>>(ccnt, cstart, ccur);
  part_scatter<<<dim3(96,6),256,0,stream>>>(ip, ccur, pbuf);
  fine_build  <<<dim3(128,6),256,0,stream>>>(ip, cstart, pbuf, stb, lists);
  sortb_kernel<<<dim3(4096,6),256,0,stream>>>(stb, lists);

  // ---- resolve loop-invariant indirections once ----
  AuxH ahp{{lists + (size_t)3*E_INC, lists + (size_t)4*E_INC, lists + (size_t)5*E_INC}};
  aux_h<<<dim3(E_INC/256,3),256,0,stream>>>(ahp, eposb);
  AuxN anp{{lists + (size_t)0*E_INC, lists + (size_t)1*E_INC, lists + (size_t)2*E_INC},
           {ei[0], ei[1], ei[2]}};
  aux_n<<<dim3(3072,3),256,0,stream>>>(anp, stb, eposb, hw, eilb, enpb, dinvb);

  // ---- h-independent attention scalars: all 6 (layer,branch) configs ----
  vv_all<<<384,256,0,stream>>>(Wh1, Wh2, att1, att2, vvb);
  s2_all<<<4096,256,0,stream>>>(hattr, vvb, s2all);

  // ---- layer0 ----
  gemm_nn<<<dim3(192,4),256,0,stream>>>(g, W0, b0, hA, FDIM, 12, 1);

  auto hyper = [&](int layer, const float* hin, const float* Whs, const float* atts,
                   const float* bcs, float* mirror){
    gemm_nn3<<<dim3(192,4,3),256,0,stream>>>(hin, Whs, xlb);
    node_alpha_b<<<dim3(3072,3),256,0,stream>>>(stb, eilb, enpb, xlb, atts,
                                                s2all + (size_t)layer*3*MM_, dinvb, an2, ah2);
    m_s  <<<12288,256,0,stream>>>(stb, ah2, xlb, mball);
    out_s<<<9216,256,0,stream>>>(stb, an2, mball, bcs, ob);
    combine_k<<<3072,256,0,stream>>>(ob, acc, mirror);
  };

  hyper(0, hA, Wh1, att1, bc1, nullptr);
  gemm_nn<<<dim3(192,4),256,0,stream>>>(acc, W1, b1, hA, FDIM, 12, 1);
  hyper(1, hA, Wh2, att2, bc2, outp + (size_t)4096*8192);  // mirrors final h to output

  // ---- projections: ng1|ng2 in one segmented launch; xs1,xs2 ----
  gemm_nn<<<dim3(128,2),256,0,stream>>>(acc + (size_t)4096*FDIM, Wg + (size_t)FDIM*CDIM,
                                        bg + CDIM, ngbuf, CDIM, 12, 1);
  gemm_nn<<<dim3(64,2),256,0,stream>>>(x, Wx + (size_t)1*FDIM*CDIM, bx + 1*CDIM, xs1, CDIM, 30, 1);
  gemm_nn<<<dim3(64,2),256,0,stream>>>(x, Wx + (size_t)2*FDIM*CDIM, bx + 2*CDIM, xs2, CDIM, 30, 1);

  // ---- result = [xs1 @ ng1^T , xs2 @ ng2^T]  (4096 x 8192) ----
  gemm_nt<<<dim3(32,32),256,0,stream>>>(xs1, ngbuf, outp, 8192, 0);
  gemm_nt<<<dim3(32,32),256,0,stream>>>(xs2, ngbuf + (size_t)4096*CDIM, outp, 8192, 4096);
}